// Round 3
// baseline (233.695 us; speedup 1.0000x reference)
//
#include <hip/hip_runtime.h>

// ---- problem constants (from reference module) ----
constexpr float DT0      = 0.0417f;
constexpr float DENSITY_ = 1000.0f;
constexpr float DXF      = 10.0f / 125.0f;   // 0.08
constexpr float INV_DXF  = 12.5f;            // exact

constexpr int DIM  = 32;
constexpr int DIM2 = DIM * DIM;

constexpr int PLN     = 3;     // own plane + 2 (gather window of own particles)
constexpr int NSLAB   = 32;    // one slab per x-plane
constexpr int THREADS = 512;
constexpr int QPC     = 1536;  // p2g queue capacity (mean ~820 worst-case nf=0)
constexpr int QGC     = 512;   // g2p queue capacity (mean ~164 worst-case)

__device__ __forceinline__ int window_min(int nf) {
    int b = 0;
    if (nf > 0) {
        b = (int)(12.5f * (float)nf - 0.5f) - 2;
        if (b < 0) b = 0;
    }
    return b;
}

// ---------------- fused P2G + G2P + loss, one block per (m, x-plane) -------
// LDS accumulator is plain f32 with native ds_add_f32 atomics (the previous
// f16x2 path fell back to an atomicCAS retry loop on ROCm7/LLVM19 - the
// removed __builtin_amdgcn_ds_atomic_fadd_v2f16 - which serialized the
// whole kernel). Velocities are normalized on read; no second LDS array.
__global__ __launch_bounds__(THREADS, 6)
void fused_kernel(const float* __restrict__ x,
                  const float* __restrict__ vol,
                  const float* __restrict__ F,
                  const float* __restrict__ C,
                  const int* __restrict__ fi_p,
                  const int* __restrict__ nf_p,
                  float* __restrict__ partials,
                  int bs, int T, int Np)
{
    // acc[(lp*DIM2 + cell)*4 + {0,1,2,3}] = {mx, my, mz, mass}
    __shared__ float acc[PLN * DIM2 * 4];        // 48 KB
    __shared__ unsigned short qp[QPC];           // n | rel<<11   (3 KB)
    __shared__ unsigned short qg[QGC];           // n             (1 KB)
    __shared__ int cnt[2];
    __shared__ float wsum[THREADS / 64];

    const int fi = fi_p[0], nf = nf_p[0];
    const int start_t = (fi == 1) ? 1 : 0;
    const int TS = (T - 2) - start_t;
    const int M  = bs * TS;

    const int m    = blockIdx.x >> 5;            // / NSLAB
    const int slab = blockIdx.x & (NSLAB - 1);   // own x-plane
    const int tid  = threadIdx.x;
    const int lane = tid & 63;

    // ---- init ----
    {
        float4* av = (float4*)acc;
        const float4 z4 = make_float4(0.f, 0.f, 0.f, 0.f);
        for (int i = tid; i < PLN * DIM2; i += THREADS) av[i] = z4;
        if (tid < 2) cnt[tid] = 0;
    }
    __syncthreads();

    const int bmin = window_min(nf);
    const float nff = (float)nf;
    const float dT = DT0 * (float)fi;
    const float inv2dT = 1.0f / (2.0f * dT);

    int b = 0, t = 0;
    const float* x0s = nullptr;
    const float* x2s = nullptr;
    const float* Cs  = nullptr;
    const float* vs  = nullptr;
    if (m < M) {
        b = m / TS;
        t = (m - b * TS) + start_t;
        x0s = x + (((size_t)b * T + t)     * Np) * 3;
        x2s = x + (((size_t)b * T + t + 2) * Np) * 3;
        Cs  = C + (((size_t)b * T + t)     * Np) * 9;
        vs  = vol + (size_t)b * Np;
    }

    // ---- phase 1: scan particles, ballot-compact p2g + g2p queues ----
    if (m < M) {
        for (int n = tid; n < Np; n += THREADS) {
            float a0 = x0s[3 * n];
            if (nf > 0) a0 = a0 * 2.0f + nff;
            const float gp0 = a0 * INV_DXF;
            const int b0 = (int)(gp0 - 0.5f);
            const int l0 = b0 - bmin;
            const int rel = l0 - slab + 2;           // contributor iff 0..4
            const bool mP = ((unsigned)rel < 5u);
            const bool mG = (l0 == slab);

            unsigned long long mk = __ballot(mP);
            if (mk) {
                const int leader = __ffsll(mk) - 1;
                const int pre = __popcll(mk & ((1ull << lane) - 1ull));
                int base = 0;
                if (lane == leader) base = atomicAdd(&cnt[0], __popcll(mk));
                base = __shfl(base, leader, 64);
                if (mP && base + pre < QPC)
                    qp[base + pre] = (unsigned short)(n | (rel << 11));
            }
            mk = __ballot(mG);
            if (mk) {
                const int leader = __ffsll(mk) - 1;
                const int pre = __popcll(mk & ((1ull << lane) - 1ull));
                int base = 0;
                if (lane == leader) base = atomicAdd(&cnt[1], __popcll(mk));
                base = __shfl(base, leader, 64);
                if (mG && base + pre < QGC)
                    qg[base + pre] = (unsigned short)n;
            }
        }
    }
    __syncthreads();

    // ---- phase 2: dense P2G over queue (native f32 LDS atomics) ----
    if (m < M) {
        const int np2g = min(cnt[0], QPC);
        for (int e = tid; e < np2g; e += THREADS) {
            const int ent = qp[e];
            const int n   = ent & 2047;
            const int rel = ent >> 11;               // 0..4

            float a0 = x0s[3 * n], a1 = x0s[3 * n + 1], a2 = x0s[3 * n + 2];
            float c0 = x2s[3 * n], c1 = x2s[3 * n + 1], c2 = x2s[3 * n + 2];
            const float mass = DENSITY_ * vs[n];
            float Cm[9];
#pragma unroll
            for (int r = 0; r < 9; ++r) Cm[r] = Cs[9 * n + r];

            if (nf > 0) {
                a0 = a0 * 2.0f + nff; a1 = a1 * 2.0f + nff; a2 = a2 * 2.0f + nff;
                c0 = c0 * 2.0f + nff; c1 = c1 * 2.0f + nff; c2 = c2 * 2.0f + nff;
            }
            const float gp0 = a0 * INV_DXF;
            const int   b0  = (int)(gp0 - 0.5f);
            const float fx0 = gp0 - (float)b0;
            const float gp1 = a1 * INV_DXF;
            const int   b1  = (int)(gp1 - 0.5f);
            const float fx1 = gp1 - (float)b1;
            const float gp2 = a2 * INV_DXF;
            const int   b2  = (int)(gp2 - 0.5f);
            const float fx2 = gp2 - (float)b2;
            const int l1 = b1 - bmin, l2 = b2 - bmin;

            const float pv0 = (c0 - a0) * inv2dT;
            const float pv1 = (c1 - a1) * inv2dT;
            const float pv2 = (c2 - a2) * inv2dT;

            float w0a[3], w1a[3], w2a[3];
            w0a[0] = 0.5f * (1.5f - fx0) * (1.5f - fx0);
            w0a[1] = 0.75f - (fx0 - 1.0f) * (fx0 - 1.0f);
            w0a[2] = 0.5f * (fx0 - 0.5f) * (fx0 - 0.5f);
            w1a[0] = 0.5f * (1.5f - fx1) * (1.5f - fx1);
            w1a[1] = 0.75f - (fx1 - 1.0f) * (fx1 - 1.0f);
            w1a[2] = 0.5f * (fx1 - 0.5f) * (fx1 - 0.5f);
            w2a[0] = 0.5f * (1.5f - fx2) * (1.5f - fx2);
            w2a[1] = 0.75f - (fx2 - 1.0f) * (fx2 - 1.0f);
            w2a[2] = 0.5f * (fx2 - 0.5f) * (fx2 - 0.5f);

            // velocity at (i=0,j=0,k=0); affine increments in i, j, k
            const float dpx0 = (-fx0) * DXF;
            const float dpy0 = (-fx1) * DXF;
            const float dpz0 = (-fx2) * DXF;
            float vix = pv0 + Cm[0]*dpx0 + Cm[1]*dpy0 + Cm[2]*dpz0;
            float viy = pv1 + Cm[3]*dpx0 + Cm[4]*dpy0 + Cm[5]*dpz0;
            float viz = pv2 + Cm[6]*dpx0 + Cm[7]*dpy0 + Cm[8]*dpz0;
            const float dix = Cm[0] * DXF, diy = Cm[3] * DXF, diz = Cm[6] * DXF;
            const float djx = Cm[1] * DXF, djy = Cm[4] * DXF, djz = Cm[7] * DXF;
            const float dkx = Cm[2] * DXF, dky = Cm[5] * DXF, dkz = Cm[8] * DXF;

            int lp = rel - 2;                        // local plane for i=0
#pragma unroll
            for (int i = 0; i < 3; ++i) {
                if ((unsigned)lp < (unsigned)PLN) {
                    const float wim = mass * w0a[i];
                    float* pb = acc + lp * (DIM2 * 4);
                    float vjx = vix, vjy = viy, vjz = viz;
#pragma unroll
                    for (int j = 0; j < 3; ++j) {
                        const int lj = min(max(l1 + j, 0), DIM - 1);
                        const float wijm = wim * w1a[j];
                        float vx = vjx, vy = vjy, vz = vjz;
#pragma unroll
                        for (int k = 0; k < 3; ++k) {
                            const int lk = min(max(l2 + k, 0), DIM - 1);
                            const float mw = wijm * w2a[k];
                            float* cp = pb + (lj * DIM + lk) * 4;
                            atomicAdd(cp + 0, mw * vx);
                            atomicAdd(cp + 1, mw * vy);
                            atomicAdd(cp + 2, mw * vz);
                            atomicAdd(cp + 3, mw);
                            vx += dkx; vy += dky; vz += dkz;
                        }
                        vjx += djx; vjy += djy; vjz += djz;
                    }
                }
                vix += dix; viy += diy; viz += diz;
                ++lp;
            }
        }
    }
    __syncthreads();

    // ---- phase 3: G2P + loss over own particles (4 lanes per particle);
    //      velocities normalized on read (no second LDS array) ----
    float s = 0.0f;
    if (m < M) {
        const int ng = min(cnt[1], QGC);
        const int q  = tid & 3;
        const float4* accv = (const float4*)acc;
        for (int e = tid >> 2; e < ng; e += THREADS / 4) {
            const int n = qg[e];

            float a0 = x0s[3 * n], a1 = x0s[3 * n + 1], a2 = x0s[3 * n + 2];
            if (nf > 0) {
                a0 = a0 * 2.0f + nff; a1 = a1 * 2.0f + nff; a2 = a2 * 2.0f + nff;
            }
            float fxv[3]; int lb1, lb2;
            {
                const float gp0 = a0 * INV_DXF;
                const int   b0  = (int)(gp0 - 0.5f);
                fxv[0] = gp0 - (float)b0;
                const float gp1 = a1 * INV_DXF;
                const int   b1  = (int)(gp1 - 0.5f);
                fxv[1] = gp1 - (float)b1;
                const float gp2 = a2 * INV_DXF;
                const int   b2  = (int)(gp2 - 0.5f);
                fxv[2] = gp2 - (float)b2;
                lb1 = b1 - bmin; lb2 = b2 - bmin;
            }
            float w[3][3], dw[3][3];
#pragma unroll
            for (int d = 0; d < 3; ++d) {
                w[d][0] = 0.5f * (1.5f - fxv[d]) * (1.5f - fxv[d]);
                w[d][1] = 0.75f - (fxv[d] - 1.0f) * (fxv[d] - 1.0f);
                w[d][2] = 0.5f * (fxv[d] - 0.5f) * (fxv[d] - 0.5f);
                dw[d][0] = fxv[d] - 1.5f;
                dw[d][1] = -2.0f * (fxv[d] - 1.0f);
                dw[d][2] = fxv[d] - 0.5f;
            }

            float nF[9] = {0,0,0,0,0,0,0,0,0};
#pragma unroll
            for (int o = q; o < 27; o += 4) {
                const int i = o / 9, j = (o / 3) % 3, k = o % 3;
                const int lj = min(max(lb1 + j, 0), DIM - 1);
                const int lk = min(max(lb2 + k, 0), DIM - 1);
                const float4 g = accv[i * DIM2 + lj * DIM + lk];
                const float inv = (g.w > 1e-15f) ? 1.0f / g.w : 1.0f;
                const float gx = g.x * inv, gy = g.y * inv, gz = g.z * inv;
                const float dwx = dw[0][i] *  w[1][j] *  w[2][k] * INV_DXF;
                const float dwy =  w[0][i] * dw[1][j] *  w[2][k] * INV_DXF;
                const float dwz =  w[0][i] *  w[1][j] * dw[2][k] * INV_DXF;
                nF[0] += gx * dwx; nF[1] += gx * dwy; nF[2] += gx * dwz;
                nF[3] += gy * dwx; nF[4] += gy * dwy; nF[5] += gy * dwz;
                nF[6] += gz * dwx; nF[7] += gz * dwy; nF[8] += gz * dwz;
            }
#pragma unroll
            for (int d = 1; d < 4; d <<= 1) {
#pragma unroll
                for (int r = 0; r < 9; ++r) nF[r] += __shfl_xor(nF[r], d, 64);
            }

            // epilogue spread over the 4 quad lanes (each has full nF)
            const float* pF  = F + (((size_t)b * T + t)     * Np + n) * 9;
            const float* pFn = F + (((size_t)b * T + t + 1) * Np + n) * 9;
            float Fm[9];
#pragma unroll
            for (int i = 0; i < 9; ++i) Fm[i] = pF[i];
#pragma unroll
            for (int ee = q; ee < 9; ee += 4) {
                const int a = ee / 3, c = ee - 3 * a;
                const float fp = Fm[a * 3 + c] + dT *
                    (nF[a * 3 + 0] * Fm[0 + c] +
                     nF[a * 3 + 1] * Fm[3 + c] +
                     nF[a * 3 + 2] * Fm[6 + c]);
                s += fabsf(fp - pFn[ee]);
            }
        }
        s *= (float)TS / ((float)M * (float)Np * 9.0f);
    }

    // ---- block reduction -> partials ----
#pragma unroll
    for (int o = 32; o > 0; o >>= 1) s += __shfl_down(s, o, 64);
    if (lane == 0) wsum[tid >> 6] = s;
    __syncthreads();
    if (tid == 0) {
        float tot = 0.0f;
#pragma unroll
        for (int w2 = 0; w2 < THREADS / 64; ++w2) tot += wsum[w2];
        partials[blockIdx.x] = tot;
    }
}

// ---------------- final reduce ---------------------------------------------
__global__ __launch_bounds__(256)
void reduce_kernel(const float* __restrict__ partials, int n,
                   float* __restrict__ out)
{
    float s = 0.0f;
    for (int i = threadIdx.x; i < n; i += 256) s += partials[i];
#pragma unroll
    for (int o = 32; o > 0; o >>= 1) s += __shfl_down(s, o, 64);
    __shared__ float wsum[4];
    const int lane = threadIdx.x & 63;
    const int wid  = threadIdx.x >> 6;
    if (lane == 0) wsum[wid] = s;
    __syncthreads();
    if (threadIdx.x == 0) out[0] = wsum[0] + wsum[1] + wsum[2] + wsum[3];
}

extern "C" void kernel_launch(void* const* d_in, const int* in_sizes, int n_in,
                              void* d_out, int out_size, void* d_ws, size_t ws_size,
                              hipStream_t stream) {
    const float* x   = (const float*)d_in[0];
    const float* vol = (const float*)d_in[1];
    const float* F   = (const float*)d_in[2];
    const float* C   = (const float*)d_in[3];
    const int*   fi  = (const int*)d_in[4];
    const int*   nf  = (const int*)d_in[5];

    const int Np = 2048;
    const int bs = in_sizes[1] / Np;                 // 2
    const int T  = in_sizes[0] / (bs * Np * 3);      // 16
    const int MMAX = bs * (T - 2);                   // 28
    const int NBLK = MMAX * NSLAB;                   // 896

    float* partials = (float*)d_ws;

    fused_kernel<<<NBLK, THREADS, 0, stream>>>(x, vol, F, C, fi, nf,
                                               partials, bs, T, Np);
    reduce_kernel<<<1, 256, 0, stream>>>(partials, NBLK, (float*)d_out);
}

// Round 4
// 90.462 us; speedup vs baseline: 2.5834x; 2.5834x over previous
//
#include <hip/hip_runtime.h>

// ---- problem constants (from reference module) ----
constexpr float DT0      = 0.0417f;
constexpr float DENSITY_ = 1000.0f;
constexpr float DXF      = 10.0f / 125.0f;   // 0.08
constexpr float INV_DXF  = 12.5f;            // exact

constexpr int DIM  = 32;
constexpr int DIM2 = DIM * DIM;

constexpr int SLAB    = 4;     // own x-planes per block
constexpr int PLN     = 6;     // acc covers planes [s4, s4+5] (own 4 + 2 gather halo)
constexpr int NSLAB   = 8;
constexpr int THREADS = 1024;
constexpr int QPC     = 2048;  // p2g queue capacity (worst-case nf=0 ~1600)
constexpr int QGC     = 1024;  // g2p queue capacity (worst-case ~700)

// fixed-point scales for integer (native ds_add_u64) accumulation
constexpr float MSCALE = 262144.0f;  // 2^18 for mass  (max cell sum ~1.1e9 < 2^32)
constexpr float PSCALE = 4096.0f;    // 2^12 for momentum (|v|<32, margin ~4x)
constexpr float VOFF   = 32.0f;      // bias keeps z-momentum field non-negative

using u32 = unsigned int;
using u64 = unsigned long long;

__device__ __forceinline__ int window_min(int nf) {
    int b = 0;
    if (nf > 0) {
        b = (int)(12.5f * (float)nf - 0.5f) - 2;
        if (b < 0) b = 0;
    }
    return b;
}

// ---------------- fused P2G + G2P + loss, one block per (m, 4-plane slab) --
// P2G scatter uses 2 native integer ds_add_u64 per cell-contribution:
//   A = (momx_i32 << 32) | mass_u32(2^18)      (mass positive, no carry into hi)
//   B = (momy_i32 << 32) | (mw*(vz+32))(2^12)  (biased z-mom positive)
// Decode: momz = B.lo - (A.lo >> 1)  since 32*mass*2^12 = A.lo/2.
// This replaces the fp atomicAdd/CAS paths that R2/R3 showed cost ~5 cyc per
// atomic lane-op and dominated the whole kernel.
__global__ __launch_bounds__(THREADS)
void fused_kernel(const float* __restrict__ x,
                  const float* __restrict__ vol,
                  const float* __restrict__ F,
                  const float* __restrict__ C,
                  const int* __restrict__ fi_p,
                  const int* __restrict__ nf_p,
                  float* __restrict__ partials,
                  int bs, int T, int Np)
{
    __shared__ u64 acc[PLN * DIM2 * 2];          // 96 KB ; later aliased float4
    __shared__ unsigned short qp[QPC];           // n | rel<<11    (4 KB)
    __shared__ unsigned short qg[QGC];           // n | l0loc<<11  (2 KB)
    __shared__ int cnt[2];
    __shared__ float wsum[THREADS / 64];

    const int fi = fi_p[0], nf = nf_p[0];
    const int start_t = (fi == 1) ? 1 : 0;
    const int TS = (T - 2) - start_t;
    const int M  = bs * TS;

    const int m    = blockIdx.x >> 3;            // / NSLAB
    const int slab = blockIdx.x & (NSLAB - 1);
    const int s4   = slab * SLAB;                // acc covers planes s4..s4+5
    const int tid  = threadIdx.x;
    const int lane = tid & 63;

    // ---- init ----
    for (int i = tid; i < PLN * DIM2 * 2; i += THREADS) acc[i] = 0ull;
    if (tid < 2) cnt[tid] = 0;
    __syncthreads();

    const int bmin = window_min(nf);
    const float nff = (float)nf;
    const float dT = DT0 * (float)fi;
    const float inv2dT = 1.0f / (2.0f * dT);

    int b = 0, t = 0;
    const float* x0s = nullptr;
    const float* x2s = nullptr;
    const float* Cs  = nullptr;
    const float* vs  = nullptr;
    if (m < M) {
        b = m / TS;
        t = (m - b * TS) + start_t;
        x0s = x + (((size_t)b * T + t)     * Np) * 3;
        x2s = x + (((size_t)b * T + t + 2) * Np) * 3;
        Cs  = C + (((size_t)b * T + t)     * Np) * 9;
        vs  = vol + (size_t)b * Np;
    }

    // ---- phase 1: scan particles, ballot-compact p2g + g2p queues ----
    if (m < M) {
        for (int n = tid; n < Np; n += THREADS) {
            float a0 = x0s[3 * n];
            if (nf > 0) a0 = a0 * 2.0f + nff;
            const float gp0 = a0 * INV_DXF;
            const int b0 = (int)(gp0 - 0.5f);
            const int l0 = b0 - bmin;
            const int rel = l0 - s4 + 2;             // queued iff 0..7
            const bool mP = ((unsigned)rel < 8u);
            const int l0loc = l0 - s4;
            const bool mG = ((unsigned)l0loc < (unsigned)SLAB);

            unsigned long long mk = __ballot(mP);
            if (mk) {
                const int leader = __ffsll(mk) - 1;
                const int pre = __popcll(mk & ((1ull << lane) - 1ull));
                int base = 0;
                if (lane == leader) base = atomicAdd(&cnt[0], __popcll(mk));
                base = __shfl(base, leader, 64);
                if (mP && base + pre < QPC)
                    qp[base + pre] = (unsigned short)(n | (rel << 11));
            }
            mk = __ballot(mG);
            if (mk) {
                const int leader = __ffsll(mk) - 1;
                const int pre = __popcll(mk & ((1ull << lane) - 1ull));
                int base = 0;
                if (lane == leader) base = atomicAdd(&cnt[1], __popcll(mk));
                base = __shfl(base, leader, 64);
                if (mG && base + pre < QGC)
                    qg[base + pre] = (unsigned short)(n | (l0loc << 11));
            }
        }
    }
    __syncthreads();

    // ---- phase 2: dense P2G over queue (2x native ds_add_u64 per cell) ----
    if (m < M) {
        const int np2g = min(cnt[0], QPC);
        for (int e = tid; e < np2g; e += THREADS) {
            const int ent = qp[e];
            const int n   = ent & 2047;
            const int rel = ent >> 11;               // 0..7

            float a0 = x0s[3 * n], a1 = x0s[3 * n + 1], a2 = x0s[3 * n + 2];
            float c0 = x2s[3 * n], c1 = x2s[3 * n + 1], c2 = x2s[3 * n + 2];
            const float mass = DENSITY_ * vs[n];
            float Cm[9];
#pragma unroll
            for (int r = 0; r < 9; ++r) Cm[r] = Cs[9 * n + r];

            if (nf > 0) {
                a0 = a0 * 2.0f + nff; a1 = a1 * 2.0f + nff; a2 = a2 * 2.0f + nff;
                c0 = c0 * 2.0f + nff; c1 = c1 * 2.0f + nff; c2 = c2 * 2.0f + nff;
            }
            const float gp0 = a0 * INV_DXF;
            const int   b0  = (int)(gp0 - 0.5f);
            const float fx0 = gp0 - (float)b0;
            const float gp1 = a1 * INV_DXF;
            const int   b1  = (int)(gp1 - 0.5f);
            const float fx1 = gp1 - (float)b1;
            const float gp2 = a2 * INV_DXF;
            const int   b2  = (int)(gp2 - 0.5f);
            const float fx2 = gp2 - (float)b2;
            const int l1 = b1 - bmin, l2 = b2 - bmin;

            const float pv0 = (c0 - a0) * inv2dT;
            const float pv1 = (c1 - a1) * inv2dT;
            const float pv2 = (c2 - a2) * inv2dT;

            float w0a[3], w1a[3], w2a[3];
            w0a[0] = 0.5f * (1.5f - fx0) * (1.5f - fx0);
            w0a[1] = 0.75f - (fx0 - 1.0f) * (fx0 - 1.0f);
            w0a[2] = 0.5f * (fx0 - 0.5f) * (fx0 - 0.5f);
            w1a[0] = 0.5f * (1.5f - fx1) * (1.5f - fx1);
            w1a[1] = 0.75f - (fx1 - 1.0f) * (fx1 - 1.0f);
            w1a[2] = 0.5f * (fx1 - 0.5f) * (fx1 - 0.5f);
            w2a[0] = 0.5f * (1.5f - fx2) * (1.5f - fx2);
            w2a[1] = 0.75f - (fx2 - 1.0f) * (fx2 - 1.0f);
            w2a[2] = 0.5f * (fx2 - 0.5f) * (fx2 - 0.5f);

            // velocity at (i=0,j=0,k=0); affine increments in i, j, k
            const float dpx0 = (-fx0) * DXF;
            const float dpy0 = (-fx1) * DXF;
            const float dpz0 = (-fx2) * DXF;
            float vix = pv0 + Cm[0]*dpx0 + Cm[1]*dpy0 + Cm[2]*dpz0;
            float viy = pv1 + Cm[3]*dpx0 + Cm[4]*dpy0 + Cm[5]*dpz0;
            float viz = pv2 + Cm[6]*dpx0 + Cm[7]*dpy0 + Cm[8]*dpz0;
            const float dix = Cm[0] * DXF, diy = Cm[3] * DXF, diz = Cm[6] * DXF;
            const float djx = Cm[1] * DXF, djy = Cm[4] * DXF, djz = Cm[7] * DXF;
            const float dkx = Cm[2] * DXF, dky = Cm[5] * DXF, dkz = Cm[8] * DXF;

            const bool fastp = (l1 >= 0 && l1 <= DIM - 3 &&
                                l2 >= 0 && l2 <= DIM - 3);
            int lp = rel - 2;                        // local plane for i=0
#pragma unroll
            for (int i = 0; i < 3; ++i) {
                if ((unsigned)lp < (unsigned)PLN) {
                    const float wim = mass * w0a[i];
                    u64* pb = acc + lp * (DIM2 * 2);
                    float vjx = vix, vjy = viy, vjz = viz;
#pragma unroll
                    for (int j = 0; j < 3; ++j) {
                        const int lj = fastp ? (l1 + j)
                                             : min(max(l1 + j, 0), DIM - 1);
                        const float wijm = wim * w1a[j];
                        float vx = vjx, vy = vjy, vz = vjz;
#pragma unroll
                        for (int k = 0; k < 3; ++k) {
                            const int lk = fastp ? (l2 + k)
                                                 : min(max(l2 + k, 0), DIM - 1);
                            const float mw = wijm * w2a[k];
                            const float pm = mw * PSCALE;
                            const u32 am = (u32)(mw * MSCALE);
                            const u32 ix = (u32)(int)(pm * vx);
                            const u32 iy = (u32)(int)(pm * vy);
                            const u32 iz = (u32)(int)(pm * (vz + VOFF));
                            u64* cp = pb + (lj * DIM + lk) * 2;
                            atomicAdd(cp + 0, ((u64)ix << 32) | (u64)am);
                            atomicAdd(cp + 1, ((u64)iy << 32) | (u64)iz);
                            vx += dkx; vy += dky; vz += dkz;
                        }
                        vjx += djx; vjy += djy; vjz += djz;
                    }
                }
                vix += dix; viy += diy; viz += diz;
                ++lp;
            }
        }
    }
    __syncthreads();

    // ---- phase 3: decode fixed-point, normalize, store float4 vel in place -
    for (int c = tid; c < PLN * DIM2; c += THREADS) {
        const u64 A = acc[c * 2 + 0];
        const u64 B = acc[c * 2 + 1];
        const u32 mass_u = (u32)A;
        const int momx = (int)(u32)(A >> 32);
        const int momy = (int)(u32)(B >> 32);
        const int momz = (int)((u32)B - (mass_u >> 1));   // un-bias (32*m*2^12)
        // v = (mom/2^12) / (mass/2^18) = 64*mom/mass_u ; mass==0 -> divide by 1
        const float inv = (mass_u != 0u) ? 64.0f / (float)mass_u
                                         : (1.0f / 4096.0f);
        ((float4*)acc)[c] = make_float4((float)momx * inv,
                                        (float)momy * inv,
                                        (float)momz * inv, 0.0f);
    }
    __syncthreads();

    // ---- phase 4: G2P + loss over own particles (4 lanes per particle) ----
    float s = 0.0f;
    if (m < M) {
        const int ng = min(cnt[1], QGC);
        const int q  = tid & 3;
        const float4* vel = (const float4*)acc;
        for (int e = tid >> 2; e < ng; e += THREADS / 4) {
            const int ent   = qg[e];
            const int n     = ent & 2047;
            const int l0loc = ent >> 11;             // 0..3

            float a0 = x0s[3 * n], a1 = x0s[3 * n + 1], a2 = x0s[3 * n + 2];
            if (nf > 0) {
                a0 = a0 * 2.0f + nff; a1 = a1 * 2.0f + nff; a2 = a2 * 2.0f + nff;
            }
            float fxv[3]; int lb1, lb2;
            {
                const float gp0 = a0 * INV_DXF;
                const int   b0  = (int)(gp0 - 0.5f);
                fxv[0] = gp0 - (float)b0;
                const float gp1 = a1 * INV_DXF;
                const int   b1  = (int)(gp1 - 0.5f);
                fxv[1] = gp1 - (float)b1;
                const float gp2 = a2 * INV_DXF;
                const int   b2  = (int)(gp2 - 0.5f);
                fxv[2] = gp2 - (float)b2;
                lb1 = b1 - bmin; lb2 = b2 - bmin;
            }
            float w[3][3], dw[3][3];
#pragma unroll
            for (int d = 0; d < 3; ++d) {
                w[d][0] = 0.5f * (1.5f - fxv[d]) * (1.5f - fxv[d]);
                w[d][1] = 0.75f - (fxv[d] - 1.0f) * (fxv[d] - 1.0f);
                w[d][2] = 0.5f * (fxv[d] - 0.5f) * (fxv[d] - 0.5f);
                dw[d][0] = fxv[d] - 1.5f;
                dw[d][1] = -2.0f * (fxv[d] - 1.0f);
                dw[d][2] = fxv[d] - 0.5f;
            }

            float nF[9] = {0,0,0,0,0,0,0,0,0};
#pragma unroll
            for (int o = q; o < 27; o += 4) {
                const int i = o / 9, j = (o / 3) % 3, k = o % 3;
                const int lp = min(max(l0loc + i, 0), PLN - 1);
                const int lj = min(max(lb1 + j, 0), DIM - 1);
                const int lk = min(max(lb2 + k, 0), DIM - 1);
                const float4 g = vel[lp * DIM2 + lj * DIM + lk];
                const float dwx = dw[0][i] *  w[1][j] *  w[2][k] * INV_DXF;
                const float dwy =  w[0][i] * dw[1][j] *  w[2][k] * INV_DXF;
                const float dwz =  w[0][i] *  w[1][j] * dw[2][k] * INV_DXF;
                nF[0] += g.x * dwx; nF[1] += g.x * dwy; nF[2] += g.x * dwz;
                nF[3] += g.y * dwx; nF[4] += g.y * dwy; nF[5] += g.y * dwz;
                nF[6] += g.z * dwx; nF[7] += g.z * dwy; nF[8] += g.z * dwz;
            }
#pragma unroll
            for (int d = 1; d < 4; d <<= 1) {
#pragma unroll
                for (int r = 0; r < 9; ++r) nF[r] += __shfl_xor(nF[r], d, 64);
            }

            // epilogue spread over the 4 quad lanes (each has full nF)
            const float* pF  = F + (((size_t)b * T + t)     * Np + n) * 9;
            const float* pFn = F + (((size_t)b * T + t + 1) * Np + n) * 9;
            float Fm[9];
#pragma unroll
            for (int i = 0; i < 9; ++i) Fm[i] = pF[i];
#pragma unroll
            for (int ee = q; ee < 9; ee += 4) {
                const int a = ee / 3, c = ee - 3 * a;
                const float fp = Fm[a * 3 + c] + dT *
                    (nF[a * 3 + 0] * Fm[0 + c] +
                     nF[a * 3 + 1] * Fm[3 + c] +
                     nF[a * 3 + 2] * Fm[6 + c]);
                s += fabsf(fp - pFn[ee]);
            }
        }
        s *= (float)TS / ((float)M * (float)Np * 9.0f);
    }

    // ---- block reduction -> partials ----
#pragma unroll
    for (int o = 32; o > 0; o >>= 1) s += __shfl_down(s, o, 64);
    if (lane == 0) wsum[tid >> 6] = s;
    __syncthreads();
    if (tid == 0) {
        float tot = 0.0f;
#pragma unroll
        for (int w2 = 0; w2 < THREADS / 64; ++w2) tot += wsum[w2];
        partials[blockIdx.x] = tot;
    }
}

// ---------------- final reduce ---------------------------------------------
__global__ __launch_bounds__(256)
void reduce_kernel(const float* __restrict__ partials, int n,
                   float* __restrict__ out)
{
    float s = 0.0f;
    for (int i = threadIdx.x; i < n; i += 256) s += partials[i];
#pragma unroll
    for (int o = 32; o > 0; o >>= 1) s += __shfl_down(s, o, 64);
    __shared__ float wsum[4];
    const int lane = threadIdx.x & 63;
    const int wid  = threadIdx.x >> 6;
    if (lane == 0) wsum[wid] = s;
    __syncthreads();
    if (threadIdx.x == 0) out[0] = wsum[0] + wsum[1] + wsum[2] + wsum[3];
}

extern "C" void kernel_launch(void* const* d_in, const int* in_sizes, int n_in,
                              void* d_out, int out_size, void* d_ws, size_t ws_size,
                              hipStream_t stream) {
    const float* x   = (const float*)d_in[0];
    const float* vol = (const float*)d_in[1];
    const float* F   = (const float*)d_in[2];
    const float* C   = (const float*)d_in[3];
    const int*   fi  = (const int*)d_in[4];
    const int*   nf  = (const int*)d_in[5];

    const int Np = 2048;
    const int bs = in_sizes[1] / Np;                 // 2
    const int T  = in_sizes[0] / (bs * Np * 3);      // 16
    const int MMAX = bs * (T - 2);                   // 28
    const int NBLK = MMAX * NSLAB;                   // 224

    float* partials = (float*)d_ws;

    fused_kernel<<<NBLK, THREADS, 0, stream>>>(x, vol, F, C, fi, nf,
                                               partials, bs, T, Np);
    reduce_kernel<<<1, 256, 0, stream>>>(partials, NBLK, (float*)d_out);
}